// Round 7
// baseline (312.660 us; speedup 1.0000x reference)
//
#include <hip/hip_runtime.h>

// ===== Problem dims =====
// B=32, L=512 -> M = 16384 rows. Inputs fp32, OUTPUTS fp32.
// GEMM1(proj): A=[emb|lang] K=640 (reg-staged fp32->f16), N=512, tanh, s1/s2.
// GEMM1b(aux): A=hidden K=800 (reg-staged, 25 exact BK32 tiles), tanh->aux_cat.
// GEMM2(heads): A=aux_cat (async16 depth-2), N=820 pad 1024, arcs fused.
// NEW GEOMETRY (R7): 128x128 tile, BK=32, 4 waves (wave-tile 64x64, acc=64),
// __launch_bounds__(256,4): <=128 VGPR + 34-41KB LDS -> 4 blocks/CU =
// 4 waves/SIMD (2x TLP vs R6). Free-run 1 barrier/tile, R6 A-pin discipline.
// gemm2: 3 A-buffers, A(t+2) prefetch, counted vmcnt(2) at tile end (T4).
// LDS swizzle: slot p = kappa ^ (r&3) ^ ((r>>2)&3)  (<=2-way, free).
// 3 launches: setup -> gemm01 (128x8) -> gemm2+arcs (128x8).

using f16   = _Float16;
using f16x4 = __attribute__((ext_vector_type(4))) _Float16;
using f16x8 = __attribute__((ext_vector_type(8))) _Float16;  // 8 f16 (4 VGPRs)
using f32x4 = __attribute__((ext_vector_type(4))) float;     // MFMA acc

__device__ __forceinline__ f16 f2h(float f) { return (f16)f; }
__device__ __forceinline__ f16x4 cvt4(float4 v) {
  return f16x4{ f2h(v.x), f2h(v.y), f2h(v.z), f2h(v.w) };
}

// fast tanh: 1 - 2/(2^(2x*log2e)+1)
__device__ __forceinline__ float fast_tanh(float x) {
  float xc = fminf(fmaxf(x, -15.f), 15.f);
  float e  = __builtin_amdgcn_exp2f(xc * 2.885390081777927f);
  return 1.f - 2.f * __builtin_amdgcn_rcpf(e + 1.f);
}

// async global->LDS, 16B/lane; LDS dest = wave-uniform base + lane*16
__device__ __forceinline__ void async16(void* lds, const void* gp) {
  __builtin_amdgcn_global_load_lds(
      (const __attribute__((address_space(1))) unsigned int*)gp,
      (__attribute__((address_space(3))) unsigned int*)lds, 16, 0, 0);
}

// ---------------------------------------------------------------------------
// Setup (tiny): pack f16 weights + fp32 biases only.
//   W_proj[512,640] | W_auxp[512,800] | W_heads[1024,640]
// ---------------------------------------------------------------------------
__global__ __launch_bounds__(256) void setup_kernel(
    const float* __restrict__ W_arc, const float* __restrict__ b_arc,
    const float* __restrict__ W_lab, const float* __restrict__ b_lab,
    const float* __restrict__ W_aux, const float* __restrict__ b_aux,
    const float* __restrict__ W_upos, const float* __restrict__ b_upos,
    const float* __restrict__ W_xpos, const float* __restrict__ b_xpos,
    const float* __restrict__ W_attrs, const float* __restrict__ b_attrs,
    f16* __restrict__ W_proj, f16* __restrict__ W_auxp, f16* __restrict__ W_heads,
    float* __restrict__ bias_proj, float* __restrict__ bias_aux, float* __restrict__ bias_heads)
{
  const int blk = blockIdx.x, t = threadIdx.x;
  if (blk < 1360) {                          // 348,160 weight quads
    int w = blk * 256 + t;
    const float* src = nullptr;
    f16* dst;
    if (w < 81920) {                         // W_proj [512,640] : 160 q/row
      int n = w / 160, s = w - n * 160;
      dst = W_proj + (size_t)w * 4;
      if (s < 150 && n < 500)
        src = (n < 100 ? W_arc + (size_t)n * 600
                       : W_lab + (size_t)(n - 100) * 600) + s * 4;
    } else if (w < 184320) {                 // W_auxp [512,800] : 200 q/row
      int w2 = w - 81920;
      dst = W_auxp + (size_t)w2 * 4;
      if (w2 < 100000) src = W_aux + (size_t)w2 * 4;   // n<500 dense
    } else {                                 // W_heads [1024,640] : 160 q/row
      int w3 = w - 184320;
      int n = w3 / 160, s = w3 - n * 160;
      dst = W_heads + (size_t)w3 * 4;
      if (s < 150 && n < 820)
        src = (n < 20 ? W_upos + (size_t)n * 600
              : n < 320 ? W_xpos + (size_t)(n - 20) * 600
                        : W_attrs + (size_t)(n - 320) * 600) + s * 4;
    }
    f16x4 h = { (f16)0.f, (f16)0.f, (f16)0.f, (f16)0.f };
    if (src) h = cvt4(*(const float4*)src);
    *(f16x4*)dst = h;
    return;
  }
  for (int idx = t; idx < 2048; idx += 256) {      // ---- biases ----
    if (idx < 512) {
      float v = 0.f;
      if (idx < 100)      v = b_arc[idx];
      else if (idx < 500) v = b_lab[idx - 100];
      bias_proj[idx] = v;
    } else if (idx < 1024) {
      int i = idx - 512;
      bias_aux[i] = (i < 500) ? b_aux[i] : 0.f;
    } else {
      int i = idx - 1024; float v = 0.f;
      if (i < 20)       v = b_upos[i];
      else if (i < 320) v = b_xpos[i - 20];
      else if (i < 820) v = b_attrs[i - 320];
      bias_heads[i] = v;
    }
  }
}

// ---------------------------------------------------------------------------
// Fused GEMM0+GEMM1, grid (128, 8), 256 threads (4 waves, 2Mx2N).
//   bny<4 : proj A=[emb|lang] K=640 NT=20; cols[100,500)->out_label;
//           bn==0: fused s1/s2 head dots
//   bny>=4: aux  A=hidden K=800 NT=25; cols[0,500)->aux_cat;
//           bn==0 also writes aux_cat lang/pad cols [500,640)
// A reg-staged fp32->f16 (R6 pin discipline); B async16 double-buffer.
// ---------------------------------------------------------------------------
__global__ __launch_bounds__(256, 4) void gemm01(
    const float* __restrict__ emb, const float* __restrict__ hidden,
    const float* __restrict__ lang_table, const int* __restrict__ lang_ids,
    const f16* __restrict__ W_proj, const f16* __restrict__ W_auxp,
    const float* __restrict__ bias_proj, const float* __restrict__ bias_aux,
    float* __restrict__ out_label, const float* __restrict__ w_head,
    float* __restrict__ s1, float* __restrict__ s2, f16* __restrict__ aux_cat)
{
  __shared__ __align__(16) f16 ldsA[2 * 4096];   // 128 rows x 32 k, 2 bufs
  __shared__ __align__(16) f16 ldsB[2 * 4096];
  __shared__ float s1red[2][128], s2red[2][128];

  const int tid  = threadIdx.x;
  const int lane = tid & 63;
  const int wave = tid >> 6;                 // 0..3
  const int wm = wave >> 1, wn = wave & 1;   // 2M x 2N, wave tile 64x64
  const int m16 = lane & 15, quad = lane >> 4;
  const int bm  = blockIdx.x;
  const int bny = blockIdx.y;                // 0..7
  const bool is0 = (bny < 4);
  const int bn  = is0 ? bny : bny - 4;
  const int K   = is0 ? 640 : 800;
  const int NT  = is0 ? 20 : 25;

  // ---- swizzle sigmas ----
  const int sigR  = (m16 & 3) ^ ((m16 >> 2) & 3);        // read rows
  const int sigS  = ((lane >> 2) & 3) ^ quad;            // staged rows
  const int kap   = lane & 3;                            // natural k-chunk

  // ---- B staging (async16, pre-swizzled source; 2 per wave per tile) ----
  const f16* Bmat = is0 ? W_proj : W_auxp;
  const int kapB = kap ^ sigS;
  const f16* gB[2];
#pragma unroll
  for (int j = 0; j < 2; ++j)
    gB[j] = Bmat + (size_t)(bn * 128 + wave * 32 + j * 16 + (lane >> 2)) * K + kapB * 8;
  const int sBoff = wave * 1024;             // + j*512 (+buf)

  // ---- A reg-staging: 2 chunks/lane (rows wave*32+i*16+(lane>>2)) ----
  const float* lrow = lang_table + (size_t)lang_ids[bm >> 2] * 100;
  const float* srcA[2];
  int dstA[2];
#pragma unroll
  for (int i = 0; i < 2; ++i) {
    const int rowL = wave * 32 + i * 16 + (lane >> 2);
    const int grow = bm * 128 + rowL;
    srcA[i] = is0 ? emb + (size_t)grow * 500 : hidden + (size_t)grow * 800;
    dstA[i] = rowL * 32 + ((kap ^ sigS) * 8);
  }
  float4 va[2], vb[2];

  // ---- ds_read bases (f16 units; + ii*512 / j*512 immediates) ----
  const int baseA = (wm * 64 + m16) * 32 + ((quad ^ sigR) * 8);
  const int baseB = (wn * 64 + m16) * 32 + ((quad ^ sigR) * 8);

  f32x4 acc[4][4] = {};
  f16x8 af[4], bf[4];

#define ASTAGE(tt) do { const int k0b = (tt) * 32 + kap * 8;                    \
    _Pragma("unroll")                                                           \
    for (int i2 = 0; i2 < 2; ++i2) {                                            \
      float4 x0 = {0.f,0.f,0.f,0.f}, x1 = {0.f,0.f,0.f,0.f};                    \
      if (is0) {                                                                \
        if (k0b < 500) { x0 = *(const float4*)(srcA[i2] + k0b);                 \
          x1 = (k0b + 4 < 500) ? *(const float4*)(srcA[i2] + k0b + 4)           \
                               : *(const float4*)(lrow); }                      \
        else if (k0b < 600) { x0 = *(const float4*)(lrow + k0b - 500);          \
                              x1 = *(const float4*)(lrow + k0b - 496); }        \
      } else { x0 = *(const float4*)(srcA[i2] + k0b);                           \
               x1 = *(const float4*)(srcA[i2] + k0b + 4); }                     \
      va[i2] = x0; vb[i2] = x1; } } while (0)

#define AWRITE(nbfA) do { _Pragma("unroll")                                     \
    for (int i2 = 0; i2 < 2; ++i2) {                                            \
      f16x8 hw = { f2h(va[i2].x), f2h(va[i2].y), f2h(va[i2].z), f2h(va[i2].w),  \
                   f2h(vb[i2].x), f2h(vb[i2].y), f2h(vb[i2].z), f2h(vb[i2].w) };\
      *(f16x8*)&ldsA[(nbfA) + dstA[i2]] = hw; } } while (0)

#define BWISSUE(tt, nbfB) do {                                                  \
    async16(&ldsB[(nbfB) + sBoff],       gB[0] + (tt) * 32);                    \
    async16(&ldsB[(nbfB) + sBoff + 512], gB[1] + (tt) * 32); } while (0)

#define RD8(bA, bB) { _Pragma("unroll")                                         \
  for (int ii = 0; ii < 4; ++ii)                                                \
    af[ii] = *(const f16x8*)&ldsA[(bA) + baseA + ii * 512];                     \
  _Pragma("unroll")                                                             \
  for (int j = 0; j < 4; ++j)                                                   \
    bf[j] = *(const f16x8*)&ldsB[(bB) + baseB + j * 512]; }
#define MM { _Pragma("unroll")                                                  \
  for (int ii = 0; ii < 4; ++ii) { _Pragma("unroll")                            \
    for (int j = 0; j < 4; ++j)                                                 \
      acc[ii][j] = __builtin_amdgcn_mfma_f32_16x16x32_f16(                      \
          af[ii], bf[j], acc[ii][j], 0, 0, 0); } }
#define SBAR __builtin_amdgcn_sched_barrier(0)
#define VM2  asm volatile("s_waitcnt vmcnt(2)" ::: "memory")
#define VM0  asm volatile("s_waitcnt vmcnt(0)" ::: "memory")
#define LGK0 asm volatile("s_waitcnt lgkmcnt(0)" ::: "memory")
#define BAR  __builtin_amdgcn_s_barrier()
#define PRIO1 __builtin_amdgcn_s_setprio(1)
#define PRIO0 __builtin_amdgcn_s_setprio(0)

  // ---- prologue: tile 0. A-loads first, then B async16; vmcnt(2) => all A
  //      landed, async16 still flying (R6 pin discipline). ----
  ASTAGE(0);
  SBAR;
  BWISSUE(0, 0);
  SBAR; VM2; SBAR;
  AWRITE(0);
  VM0;
  LGK0;
  BAR;

  int bufA = 0, bufB = 0;
  for (int t = 0; t < NT; ++t) {
    const bool st = (t + 1 < NT);
    const int nA = bufA ^ 4096, nB = bufB ^ 4096;

    if (st) ASTAGE(t + 1);
    SBAR;                                    // A issues before B async16
    if (st) BWISSUE(t + 1, nB);
    RD8(bufA, bufB);
    PRIO1; MM; PRIO0;
    if (st) {
      SBAR; VM2; SBAR;                       // 2 A-loads... (4 issued, 2 async16 after)
      AWRITE(nA);
    }
    VM0;                                     // retire async16 -> publish B
    LGK0;                                    // publish A ds_writes
    BAR;                                     // single per-tile barrier
    bufA = nA; bufB = nB;
  }
#undef ASTAGE
#undef AWRITE
#undef BWISSUE
#undef RD8
#undef MM
#undef SBAR
#undef VM2
#undef VM0
#undef LGK0
#undef BAR
#undef PRIO1
#undef PRIO0

  // ---- epilogue: row = bm*128+wm*64+ai*16+quad*4+r ; col = bn*128+wn*64+j*16+m16
  const int row0 = bm * 128 + wm * 64 + quad * 4;
  const int colT = bn * 128 + wn * 64 + m16;

  if (is0) {
    const bool haveHead = (bn == 0);
#pragma unroll
    for (int ai = 0; ai < 4; ++ai) {
      float p1r[4] = {}, p2r[4] = {};
#pragma unroll
      for (int j = 0; j < 4; ++j) {
        const int col = colT + j * 16;
        const float bcol = bias_proj[col];
        float w1c = 0.f, w2c = 0.f;
        if (haveHead && col < 100) { w1c = w_head[col]; w2c = w_head[100 + col]; }
#pragma unroll
        for (int r = 0; r < 4; ++r) {
          const int row = row0 + ai * 16 + r;
          float v = fast_tanh(acc[ai][j][r] + bcol);
          if (col >= 100 && col < 500) out_label[(size_t)row * 400 + col - 100] = v;
          p1r[r] += v * w1c;
          p2r[r] += v * w2c;
        }
      }
      if (haveHead) {
#pragma unroll
        for (int d = 1; d < 16; d <<= 1)
#pragma unroll
          for (int r = 0; r < 4; ++r) {
            p1r[r] += __shfl_xor(p1r[r], d);
            p2r[r] += __shfl_xor(p2r[r], d);
          }
        if (m16 == 0) {
#pragma unroll
          for (int r = 0; r < 4; ++r) {
            int rl = wm * 64 + ai * 16 + quad * 4 + r;
            s1red[wn][rl] = p1r[r];
            s2red[wn][rl] = p2r[r];
          }
        }
      }
    }
    if (haveHead) {
      __syncthreads();
      if (tid < 128)       s1[bm * 128 + tid] = s1red[0][tid] + s1red[1][tid];
      else                 s2[bm * 128 + tid - 128] = s2red[0][tid - 128] + s2red[1][tid - 128];
    }
  } else {
#pragma unroll
    for (int ai = 0; ai < 4; ++ai)
#pragma unroll
      for (int j = 0; j < 4; ++j) {
        const int col = colT + j * 16;
        if (col < 500) {
          const float bcol = bias_aux[col];
#pragma unroll
          for (int r = 0; r < 4; ++r) {
            const int row = row0 + ai * 16 + r;
            aux_cat[(size_t)row * 640 + col] = f2h(fast_tanh(acc[ai][j][r] + bcol));
          }
        }
      }
    if (bn == 0) {                           // bny==4: lang/pad cols [500,640)
      for (int idx = tid; idx < 128 * 35; idx += 256) {
        int rr = idx / 35, qq = idx - rr * 35;
        int col = 500 + 4 * qq;
        f16x4 h = { (f16)0.f, (f16)0.f, (f16)0.f, (f16)0.f };
        if (col < 600) h = cvt4(*(const float4*)(lrow + col - 500));
        *(f16x4*)(aux_cat + (size_t)(bm * 128 + rr) * 640 + col) = h;
      }
    }
  }
}

// ---------------------------------------------------------------------------
// Fused GEMM2 + arcs, grid (128, 8), 256 threads, free-run 1-barrier/tile.
// A depth-2 prefetch (3 buffers): A(t+2) issued at tile t, counted vmcnt(2)
// at tile end (never 0 mid-loop). B double-buffered.
//   heads GEMM A=aux_cat[16384,640] B=W_heads[1024,640] K=640 NT=20;
//   cols<20 upos | <320 xpos | <820 attrs. Then arcs rows [bm*128+bn*16,+16).
// ---------------------------------------------------------------------------
__global__ __launch_bounds__(256, 4) void gemm2_arcs(
    const f16* __restrict__ aux_cat, const f16* __restrict__ W_heads,
    const float* __restrict__ bias_heads,
    const float* __restrict__ s1, const float* __restrict__ s2,
    const float* __restrict__ b_head,
    float* __restrict__ out_arcs, float* __restrict__ out_upos,
    float* __restrict__ out_xpos, float* __restrict__ out_attrs)
{
  __shared__ __align__(16) f16 ldsA[3 * 4096];   // 3 bufs (depth-2 A)
  __shared__ __align__(16) f16 ldsB[2 * 4096];

  const int tid  = threadIdx.x;
  const int lane = tid & 63;
  const int wave = tid >> 6;
  const int wm = wave >> 1, wn = wave & 1;
  const int m16 = lane & 15, quad = lane >> 4;
  const int bm = blockIdx.x, bn = blockIdx.y;
  const int NT = 20;

  const int sigR = (m16 & 3) ^ ((m16 >> 2) & 3);
  const int sigS = ((lane >> 2) & 3) ^ quad;
  const int kapS = (lane & 3) ^ sigS;

  const f16* gA[2]; const f16* gB[2];
#pragma unroll
  for (int j = 0; j < 2; ++j) {
    const int rsub = wave * 32 + j * 16 + (lane >> 2);
    gA[j] = aux_cat + (size_t)(bm * 128 + rsub) * 640 + kapS * 8;
    gB[j] = W_heads + (size_t)(bn * 128 + rsub) * 640 + kapS * 8;
  }
  const int sOff = wave * 1024;              // + j*512 (+buf)

  const int baseA = (wm * 64 + m16) * 32 + ((quad ^ sigR) * 8);
  const int baseB = (wn * 64 + m16) * 32 + ((quad ^ sigR) * 8);

  f32x4 acc[4][4] = {};
  f16x8 af[4], bf[4];

#define SA(tt, bA) do {                                                         \
    async16(&ldsA[(bA) + sOff],       gA[0] + (tt) * 32);                       \
    async16(&ldsA[(bA) + sOff + 512], gA[1] + (tt) * 32); } while (0)
#define SB(tt, bB) do {                                                         \
    async16(&ldsB[(bB) + sOff],       gB[0] + (tt) * 32);                       \
    async16(&ldsB[(bB) + sOff + 512], gB[1] + (tt) * 32); } while (0)
#define RD8(bA, bB) { _Pragma("unroll")                                         \
  for (int ii = 0; ii < 4; ++ii)                                                \
    af[ii] = *(const f16x8*)&ldsA[(bA) + baseA + ii * 512];                     \
  _Pragma("unroll")                                                             \
  for (int j = 0; j < 4; ++j)                                                   \
    bf[j] = *(const f16x8*)&ldsB[(bB) + baseB + j * 512]; }
#define MM { _Pragma("unroll")                                                  \
  for (int ii = 0; ii < 4; ++ii) { _Pragma("unroll")                            \
    for (int j = 0; j < 4; ++j)                                                 \
      acc[ii][j] = __builtin_amdgcn_mfma_f32_16x16x32_f16(                      \
          af[ii], bf[j], acc[ii][j], 0, 0, 0); } }
#define SBAR __builtin_amdgcn_sched_barrier(0)
#define VM2  asm volatile("s_waitcnt vmcnt(2)" ::: "memory")
#define VM0  asm volatile("s_waitcnt vmcnt(0)" ::: "memory")
#define BAR  __builtin_amdgcn_s_barrier()
#define PRIO1 __builtin_amdgcn_s_setprio(1)
#define PRIO0 __builtin_amdgcn_s_setprio(0)

  // prologue: issue A(0), B(0), A(1); wait oldest 4 (A0+B0); A1 stays flying
  SA(0, 0);
  SBAR;
  SB(0, 0);
  SBAR;
  SA(1, 4096);
  VM2;
  BAR;

  int a0 = 0, a1 = 4096, a2 = 8192, b0 = 0;
  for (int t = 0; t < NT; ++t) {
    const bool st1 = (t + 1 < NT), st2 = (t + 2 < NT);

    if (st1) SB(t + 1, b0 ^ 4096);           // oldest-after-A(t+1)
    SBAR;
    if (st2) SA(t + 2, a2);
    RD8(a0, b0);
    PRIO1; MM; PRIO0;
    if (st2) VM2; else VM0;                  // retire A(t+1)+B(t+1); A(t+2) flies
    BAR;
    int rot = a0; a0 = a1; a1 = a2; a2 = rot;
    b0 ^= 4096;
  }
#undef SA
#undef SB
#undef RD8
#undef MM
#undef SBAR
#undef VM2
#undef VM0
#undef BAR
#undef PRIO1
#undef PRIO0

  const int row0 = bm * 128 + wm * 64 + quad * 4;
  const int colT = bn * 128 + wn * 64 + m16;
#pragma unroll
  for (int ai = 0; ai < 4; ++ai)
#pragma unroll
    for (int j = 0; j < 4; ++j) {
      const int col = colT + j * 16;
      const float bcol = bias_heads[col];
#pragma unroll
      for (int r = 0; r < 4; ++r) {
        const int row = row0 + ai * 16 + r;
        float v = acc[ai][j][r] + bcol;
        if (col < 20)        out_upos[(size_t)row * 20 + col] = v;
        else if (col < 320)  out_xpos[(size_t)row * 300 + col - 20] = v;
        else if (col < 820)  out_attrs[(size_t)row * 500 + col - 320] = v;
      }
    }

  // ---- arcs: 16 rows per block (rows bm*128 + bn*16 ..+16), coalesced ----
  const int r0 = bm * 128 + bn * 16;
  const int b = bm >> 2;                     // batch (rows 128-aligned)
  const float bh = b_head[0];
  const float s2a = s2[(b << 9) + tid];
  const float s2b = s2[(b << 9) + 256 + tid];
#pragma unroll
  for (int rl = 0; rl < 16; ++rl) {
    const int row = r0 + rl;
    const float s1v = s1[row] + bh;
    float* orow = out_arcs + (size_t)row * 513;
    if (tid == 0) orow[0] = 0.f;
    orow[1 + tid] = s1v + s2a;
    orow[257 + tid] = s1v + s2b;
  }
}

// ---------------------------------------------------------------------------
extern "C" void kernel_launch(void* const* d_in, const int* in_sizes, int n_in,
                              void* d_out, int out_size, void* d_ws, size_t ws_size,
                              hipStream_t stream)
{
  const float* emb      = (const float*)d_in[0];   // [32,512,500]
  const float* hidden   = (const float*)d_in[1];   // [32,512,800]
  const int*   lang_ids = (const int*)d_in[2];     // [32]
  const float* lang_tab = (const float*)d_in[3];   // [8,100]
  const float* W_arc  = (const float*)d_in[4];
  const float* b_arc  = (const float*)d_in[5];
  const float* W_lab  = (const float*)d_in[6];
  const float* b_lab  = (const float*)d_in[7];
  const float* w_head = (const float*)d_in[8];
  const float* b_head = (const float*)d_in[9];
  const float* W_aux  = (const float*)d_in[10];
  const float* b_aux  = (const float*)d_in[11];
  const float* W_upos = (const float*)d_in[12];
  const float* b_upos = (const float*)d_in[13];
  const float* W_xpos = (const float*)d_in[14];
  const float* b_xpos = (const float*)d_in[15];
  const float* W_attrs = (const float*)d_in[16];
  const float* b_attrs = (const float*)d_in[17];

  char* ws = (char*)d_ws;
  f16* aux_cat = (f16*)(ws + 0);                  // 16384*640*2 = 20,971,520
  f16* W_proj  = (f16*)(ws + 20971520);           // 512*640*2   =    655,360
  f16* W_auxp  = (f16*)(ws + 21626880);           // 512*800*2   =    819,200
  f16* W_heads = (f16*)(ws + 22446080);           // 1024*640*2  =  1,310,720
  float* bias_proj  = (float*)(ws + 23756800);    // 512*4
  float* bias_aux   = (float*)(ws + 23758848);    // 512*4
  float* bias_heads = (float*)(ws + 23760896);    // 1024*4
  float* s1         = (float*)(ws + 23764992);    // 16384*4
  float* s2         = (float*)(ws + 23830528);    // 16384*4
  // total ws use: 23,896,064 bytes

  float* out       = (float*)d_out;
  float* out_arcs  = out;                 // 8,404,992
  float* out_label = out + 8404992;       // 6,553,600
  float* out_upos  = out + 14958592;      //   327,680
  float* out_xpos  = out + 15286272;      // 4,915,200
  float* out_attrs = out + 20201472;      // 8,192,000

  setup_kernel<<<1361, 256, 0, stream>>>(
      W_arc, b_arc, W_lab, b_lab, W_aux, b_aux,
      W_upos, b_upos, W_xpos, b_xpos, W_attrs, b_attrs,
      W_proj, W_auxp, W_heads, bias_proj, bias_aux, bias_heads);

  gemm01<<<dim3(128, 8), 256, 0, stream>>>(
      emb, hidden, lang_tab, lang_ids, W_proj, W_auxp, bias_proj, bias_aux,
      out_label, w_head, s1, s2, aux_cat);

  gemm2_arcs<<<dim3(128, 8), 256, 0, stream>>>(
      aux_cat, W_heads, bias_heads, s1, s2, b_head,
      out_arcs, out_upos, out_xpos, out_attrs);
}

// Round 8
// 280.073 us; speedup vs baseline: 1.1164x; 1.1164x over previous
//
#include <hip/hip_runtime.h>

// ===== Problem dims =====
// B=32, L=512 -> M = 16384 rows. Inputs fp32, OUTPUTS fp32.
// GEMM1(proj): A=[emb|lang] K=640 (reg-staged fp32->f16), N=512 pad, tanh,
//   fused s1/s2. GEMM1b(aux): A=hidden K=800 pad 832 (reg-staged), tanh,
//   writes aux_cat (+lang/pad cols from bny==2 epilogue).
// GEMM2(heads): A=aux_cat f16 (async16 depth-2), N=820 pad 1024, arcs fused.
// R8 = R6 (best, 267us) + depth-2 prefetch on the DMA-staged operand:
//   gemm01: 3 B-buffers, B(t+2) issued at tile t; pre-AWRITE wait is
//     vmcnt(4) (retires 8 A-loads + B(t+1), keeps B(t+2) flying) -- the
//     mid-loop vmcnt(0) is GONE. s1red/s2red alias ldsA (dead post-loop)
//     to fit LDS at exactly 160 KB.
//   gemm2: 3 A-buffers, A(t+2) at tile t; end-of-tile vmcnt(4) (vmcnt(0)
//     only at the NT-2 edge). B (L2-resident weights) stays depth-1.
// Free-run: ONE s_barrier per K-tile; R6 A-pin discipline retained.
// 3 launches: setup(weights+bias) -> gemm01 (64x4) -> gemm2+arcs (64x4).

using f16   = _Float16;
using f16x4 = __attribute__((ext_vector_type(4))) _Float16;
using f16x8 = __attribute__((ext_vector_type(8))) _Float16;  // 8 f16 (4 VGPRs)
using f32x4 = __attribute__((ext_vector_type(4))) float;     // MFMA acc

__device__ __forceinline__ f16 f2h(float f) { return (f16)f; }
__device__ __forceinline__ f16x4 cvt4(float4 v) {
  return f16x4{ f2h(v.x), f2h(v.y), f2h(v.z), f2h(v.w) };
}

// fast tanh: 1 - 2/(2^(2x*log2e)+1)
__device__ __forceinline__ float fast_tanh(float x) {
  float xc = fminf(fmaxf(x, -15.f), 15.f);
  float e  = __builtin_amdgcn_exp2f(xc * 2.885390081777927f);
  return 1.f - 2.f * __builtin_amdgcn_rcpf(e + 1.f);
}

// async global->LDS, 16B/lane; LDS dest = wave-uniform base + lane*16
__device__ __forceinline__ void async16(void* lds, const void* gp) {
  __builtin_amdgcn_global_load_lds(
      (const __attribute__((address_space(1))) unsigned int*)gp,
      (__attribute__((address_space(3))) unsigned int*)lds, 16, 0, 0);
}

// ---------------------------------------------------------------------------
// Setup (tiny): pack f16 weights + fp32 biases only.
//   W_proj[512,640] | W_auxp[512,832] | W_heads[1024,640]
// ---------------------------------------------------------------------------
__global__ __launch_bounds__(256) void setup_kernel(
    const float* __restrict__ W_arc, const float* __restrict__ b_arc,
    const float* __restrict__ W_lab, const float* __restrict__ b_lab,
    const float* __restrict__ W_aux, const float* __restrict__ b_aux,
    const float* __restrict__ W_upos, const float* __restrict__ b_upos,
    const float* __restrict__ W_xpos, const float* __restrict__ b_xpos,
    const float* __restrict__ W_attrs, const float* __restrict__ b_attrs,
    f16* __restrict__ W_proj, f16* __restrict__ W_auxp, f16* __restrict__ W_heads,
    float* __restrict__ bias_proj, float* __restrict__ bias_aux, float* __restrict__ bias_heads)
{
  const int blk = blockIdx.x, t = threadIdx.x;
  if (blk < 1376) {                          // 352,256 weight quads
    int w = blk * 256 + t;
    const float* src = nullptr;
    f16* dst;
    if (w < 81920) {                         // W_proj [512,640] : 160 q/row
      int n = w / 160, s = w - n * 160;
      dst = W_proj + (size_t)w * 4;
      if (s < 150 && n < 500)
        src = (n < 100 ? W_arc + (size_t)n * 600
                       : W_lab + (size_t)(n - 100) * 600) + s * 4;
    } else if (w < 81920 + 106496) {         // W_auxp [512,832] : 208 q/row
      int w2 = w - 81920;
      int n = w2 / 208, s = w2 - n * 208;
      dst = W_auxp + (size_t)w2 * 4;
      if (s < 200 && n < 500) src = W_aux + (size_t)n * 800 + s * 4;
    } else {                                 // W_heads [1024,640] : 160 q/row
      int w3 = w - (81920 + 106496);
      int n = w3 / 160, s = w3 - n * 160;
      dst = W_heads + (size_t)w3 * 4;
      if (s < 150 && n < 820)
        src = (n < 20 ? W_upos + (size_t)n * 600
              : n < 320 ? W_xpos + (size_t)(n - 20) * 600
                        : W_attrs + (size_t)(n - 320) * 600) + s * 4;
    }
    f16x4 h = { (f16)0.f, (f16)0.f, (f16)0.f, (f16)0.f };
    if (src) h = cvt4(*(const float4*)src);
    *(f16x4*)dst = h;
    return;
  }
  for (int idx = t; idx < 2048; idx += 256) {      // ---- biases ----
    if (idx < 512) {
      float v = 0.f;
      if (idx < 100)      v = b_arc[idx];
      else if (idx < 500) v = b_lab[idx - 100];
      bias_proj[idx] = v;
    } else if (idx < 1024) {
      int i = idx - 512;
      bias_aux[i] = (i < 500) ? b_aux[i] : 0.f;
    } else {
      int i = idx - 1024; float v = 0.f;
      if (i < 20)       v = b_upos[i];
      else if (i < 320) v = b_xpos[i - 20];
      else if (i < 820) v = b_attrs[i - 320];
      bias_heads[i] = v;
    }
  }
}

// ---------------------------------------------------------------------------
// Fused GEMM0+GEMM1, grid (64, 4), 512 threads. A reg-staged from fp32.
//   bny<2 : proj A=[emb|lang|pad] K=640 NT=10; cols[100,500)->out_label;
//           bny==0: fused s1/s2 head dots
//   bny>=2: aux  A=hidden pad     K=832 NT=13; cols[0,500)->aux_cat;
//           bny==2 also writes aux_cat lang/pad cols [500,640)
// LDS 160KB: ldsA 2x16384 f16 | ldsB 3x16384 f16; s1red/s2red alias ldsA.
// ---------------------------------------------------------------------------
__global__ __launch_bounds__(512, 2) void gemm01(
    const float* __restrict__ emb, const float* __restrict__ hidden,
    const float* __restrict__ lang_table, const int* __restrict__ lang_ids,
    const f16* __restrict__ W_proj, const f16* __restrict__ W_auxp,
    const float* __restrict__ bias_proj, const float* __restrict__ bias_aux,
    float* __restrict__ out_label, const float* __restrict__ w_head,
    float* __restrict__ s1, float* __restrict__ s2, f16* __restrict__ aux_cat)
{
  __shared__ __align__(16) char smem[163840];
  f16* ldsA = (f16*)smem;                    // 2 bufs x 16384 f16 = 65,536 B
  f16* ldsB = (f16*)(smem + 65536);          // 3 bufs x 16384 f16 = 98,304 B
  float* s1redp = (float*)smem;              // [2][256] aliased (post-loop)
  float* s2redp = (float*)(smem + 2048);

  const int tid  = threadIdx.x;
  const int lane = tid & 63;
  const int wave = tid >> 6;                 // 0..7
  const int wm = wave >> 2, wn = wave & 3;   // 2M x 4N
  const int m16 = lane & 15, quad = lane >> 4;
  const int bm  = blockIdx.x;
  const int bny = blockIdx.y;                // 0..3
  const bool is0 = (bny < 2);
  const int bn  = is0 ? bny : bny - 2;
  const int K   = is0 ? 640 : 832;
  const int NT  = is0 ? 10 : 13;

  // ---- B staging (async16, pre-swizzled source) ----
  const int sr = lane >> 3;
  const int ssB = (lane & 7) ^ sr;
  const f16* Bmat = is0 ? W_proj : W_auxp;
  const f16* gB[4];
#pragma unroll
  for (int i = 0; i < 4; ++i)
    gB[i] = Bmat + (size_t)(bn * 256 + i * 64 + wave * 8 + sr) * K + ssB * 8;
  f16* sB = ldsB + wave * 512;

  // ---- A reg-staging: lane owns 4 chunks (rows wave*32+i*8+(lane>>3),
  //      slot ssA=lane&7); lang row is block-uniform (batch = bm>>1). ----
  const int ssA = lane & 7;
  const float* lrow = lang_table + (size_t)lang_ids[bm >> 1] * 100;
  const float* srcA[4];
  int dstA[4];
#pragma unroll
  for (int i = 0; i < 4; ++i) {
    const int rowA = wave * 32 + i * 8 + (lane >> 3);
    const int grow = bm * 256 + rowA;
    srcA[i] = is0 ? emb + (size_t)grow * 500 : hidden + (size_t)grow * 800;
    dstA[i] = rowA * 64 + ((ssA ^ (rowA & 7)) * 8);
  }
  float4 va[4], vb[4];

  // ---- ds_read bases ----
  const int aBase = (wm * 128 + m16) * 64;
  const int bBase = (wn * 64  + m16) * 64;
  const int sw0 = ((quad)     ^ (m16 & 7)) * 8;
  const int sw1 = ((4 | quad) ^ (m16 & 7)) * 8;

  f32x4 acc[8][4] = {};
  f16x8 af[4], bf[4];

#define ASTAGE(tt) do { const int k0b = (tt) * 64 + ssA * 8;                    \
    _Pragma("unroll")                                                           \
    for (int i2 = 0; i2 < 4; ++i2) {                                            \
      float4 x0 = {0.f,0.f,0.f,0.f}, x1 = {0.f,0.f,0.f,0.f};                    \
      if (is0) {                                                                \
        if (k0b < 500) { x0 = *(const float4*)(srcA[i2] + k0b);                 \
          x1 = (k0b + 4 < 500) ? *(const float4*)(srcA[i2] + k0b + 4)           \
                               : *(const float4*)(lrow); }                      \
        else if (k0b < 600) { x0 = *(const float4*)(lrow + k0b - 500);          \
                              x1 = *(const float4*)(lrow + k0b - 496); }        \
      } else if (k0b < 800) { x0 = *(const float4*)(srcA[i2] + k0b);            \
                              x1 = *(const float4*)(srcA[i2] + k0b + 4); }      \
      va[i2] = x0; vb[i2] = x1; } } while (0)

#define AWRITE(nbfA) do { _Pragma("unroll")                                     \
    for (int i2 = 0; i2 < 4; ++i2) {                                            \
      f16x8 hw = { f2h(va[i2].x), f2h(va[i2].y), f2h(va[i2].z), f2h(va[i2].w),  \
                   f2h(vb[i2].x), f2h(vb[i2].y), f2h(vb[i2].z), f2h(vb[i2].w) };\
      *(f16x8*)&ldsA[(nbfA) + dstA[i2]] = hw; } } while (0)

#define BWISSUE(tt, bBuf) do { const int k0w = (tt) << 6;                       \
    async16(sB + (bBuf) + 0 * 4096, gB[0] + k0w);                               \
    async16(sB + (bBuf) + 1 * 4096, gB[1] + k0w);                               \
    async16(sB + (bBuf) + 2 * 4096, gB[2] + k0w);                               \
    async16(sB + (bBuf) + 3 * 4096, gB[3] + k0w); } while (0)

#define RDA(mqv, sw, bA) { _Pragma("unroll")                                    \
  for (int ii = 0; ii < 4; ++ii)                                                \
    af[ii] = *(const f16x8*)&ldsA[(bA) + aBase + (mqv) * 4096 + ii * 1024 + (sw)]; }
#define RDB(sw, bB) { _Pragma("unroll")                                         \
  for (int j = 0; j < 4; ++j)                                                   \
    bf[j] = *(const f16x8*)&ldsB[(bB) + bBase + j * 1024 + (sw)]; }
#define MM(mqv) { _Pragma("unroll")                                             \
  for (int ii = 0; ii < 4; ++ii) { _Pragma("unroll")                            \
    for (int j = 0; j < 4; ++j)                                                 \
      acc[(mqv) * 4 + ii][j] = __builtin_amdgcn_mfma_f32_16x16x32_f16(          \
          af[ii], bf[j], acc[(mqv) * 4 + ii][j], 0, 0, 0); } }
#define SBAR __builtin_amdgcn_sched_barrier(0)
#define VM8  asm volatile("s_waitcnt vmcnt(8)" ::: "memory")
#define VM4  asm volatile("s_waitcnt vmcnt(4)" ::: "memory")
#define VM0  asm volatile("s_waitcnt vmcnt(0)" ::: "memory")
#define LGK0 asm volatile("s_waitcnt lgkmcnt(0)" ::: "memory")
#define BAR  __builtin_amdgcn_s_barrier()
#define PRIO1 __builtin_amdgcn_s_setprio(1)
#define PRIO0 __builtin_amdgcn_s_setprio(0)

  // ---- prologue: tile 0 + B(1) in flight. A-loads first (pinned), then
  //      B(0),B(1) async16; vmcnt(8) => all A landed; vmcnt(4) => B(0)
  //      landed, B(1) still flying across the barrier. ----
  ASTAGE(0);
  SBAR;
  BWISSUE(0, 0);
  BWISSUE(1, 16384);
  SBAR; VM8; SBAR;
  AWRITE(0);
  VM4;
  LGK0;
  BAR;

  int bufA = 0;
  int bB0 = 0, bB1 = 16384, bB2 = 32768;
  for (int t = 0; t < NT; ++t) {
    const int nA = bufA ^ 16384;
    const bool st1 = (t + 1 < NT), st2 = (t + 2 < NT);

    // ---- free-run tile body: no intra-tile barriers ----
    if (st1) ASTAGE(t + 1);
    SBAR;                      // A-loads issue before B async16
    if (st2) BWISSUE(t + 2, bB2);
    RDB(sw0, bB0); RDA(0, sw0, bufA);
    PRIO1; MM(0); PRIO0;
    RDA(1, sw0, bufA);
    PRIO1; MM(1); PRIO0;
    RDB(sw1, bB0); RDA(0, sw1, bufA);
    PRIO1; MM(0); PRIO0;
    RDA(1, sw1, bufA);
    PRIO1; MM(1); PRIO0;
    if (st1) {
      SBAR;
      if (st2) VM4; else VM0;  // retire A(t+1)+B(t+1); B(t+2) keeps flying
      SBAR;
      AWRITE(nA);
    }
    LGK0;                      // publish AWRITE ds_writes
    BAR;                       // single per-tile barrier
    bufA = nA;
    int tmp = bB0; bB0 = bB1; bB1 = bB2; bB2 = tmp;
  }
#undef ASTAGE
#undef AWRITE
#undef BWISSUE
#undef RDA
#undef RDB
#undef MM
#undef SBAR
#undef VM8
#undef VM4
#undef VM0
#undef LGK0
#undef BAR
#undef PRIO1
#undef PRIO0

  // ---- epilogue (s1red/s2red alias ldsA -- dead after final loop BAR) ----
  const int row0 = bm * 256 + wm * 128 + quad * 4;
  const int colT = bn * 256 + wn * 64 + m16;

  if (is0) {
    const float* bias = bias_proj;
    float p1[8][4] = {}, p2[8][4] = {};
    const bool haveHead = (bn == 0);
#pragma unroll
    for (int ai = 0; ai < 8; ++ai) {
#pragma unroll
      for (int j = 0; j < 4; ++j) {
        const int col = colT + j * 16;
        const float bcol = bias[col];
        float w1c = 0.f, w2c = 0.f;
        if (haveHead && col < 100) { w1c = w_head[col]; w2c = w_head[100 + col]; }
#pragma unroll
        for (int r = 0; r < 4; ++r) {
          const int row = row0 + ai * 16 + r;
          float v = fast_tanh(acc[ai][j][r] + bcol);
          if (col >= 100 && col < 500) out_label[(size_t)row * 400 + col - 100] = v;
          p1[ai][r] += v * w1c;
          p2[ai][r] += v * w2c;
        }
      }
    }
    if (haveHead) {
      if (wn < 2) {
#pragma unroll
        for (int d = 1; d < 16; d <<= 1)
#pragma unroll
          for (int ai = 0; ai < 8; ++ai)
#pragma unroll
            for (int r = 0; r < 4; ++r) {
              p1[ai][r] += __shfl_xor(p1[ai][r], d);
              p2[ai][r] += __shfl_xor(p2[ai][r], d);
            }
        if (m16 == 0) {
#pragma unroll
          for (int ai = 0; ai < 8; ++ai)
#pragma unroll
            for (int r = 0; r < 4; ++r) {
              int rl = wm * 128 + ai * 16 + quad * 4 + r;
              s1redp[wn * 256 + rl] = p1[ai][r];
              s2redp[wn * 256 + rl] = p2[ai][r];
            }
        }
      }
      __syncthreads();
      if (tid < 256) s1[bm * 256 + tid] = s1redp[tid] + s1redp[256 + tid];
      else { int t2 = tid - 256; s2[bm * 256 + t2] = s2redp[t2] + s2redp[256 + t2]; }
    }
  } else {
    const float* bias = bias_aux;
#pragma unroll
    for (int ai = 0; ai < 8; ++ai)
#pragma unroll
      for (int j = 0; j < 4; ++j) {
        const int col = colT + j * 16;
        if (col < 500) {
          const float bcol = bias[col];
#pragma unroll
          for (int r = 0; r < 4; ++r) {
            const int row = row0 + ai * 16 + r;
            aux_cat[(size_t)row * 640 + col] = f2h(fast_tanh(acc[ai][j][r] + bcol));
          }
        }
      }
    if (bn == 0) {                           // bny==2: lang/pad cols [500,640)
      for (int idx = tid; idx < 256 * 35; idx += 512) {
        int rr = idx / 35, qq = idx - rr * 35;
        int col = 500 + 4 * qq;
        f16x4 h = { (f16)0.f, (f16)0.f, (f16)0.f, (f16)0.f };
        if (col < 600) h = cvt4(*(const float4*)(lrow + col - 500));
        *(f16x4*)(aux_cat + (size_t)(bm * 256 + rr) * 640 + col) = h;
      }
    }
  }
}

// ---------------------------------------------------------------------------
// Fused GEMM2 + arcs, grid (64, 4), 512 threads, free-run 1-barrier/tile.
// A depth-2 (3 bufs, 96KB) + B depth-1 (2 bufs, 64KB) = 160KB LDS exactly.
// End-of-tile wait: vmcnt(4) (A(t+2) stays in flight); vmcnt(0) at edges.
//   heads GEMM A=aux_cat[16384,640] B=W_heads[1024,640] K=640 NT=10;
//   cols<20 upos | <320 xpos | <820 attrs. Then arcs rows [bm*256+bn*64,+64).
// ---------------------------------------------------------------------------
__global__ __launch_bounds__(512, 2) void gemm2_arcs(
    const f16* __restrict__ aux_cat, const f16* __restrict__ W_heads,
    const float* __restrict__ bias_heads,
    const float* __restrict__ s1, const float* __restrict__ s2,
    const float* __restrict__ b_head,
    float* __restrict__ out_arcs, float* __restrict__ out_upos,
    float* __restrict__ out_xpos, float* __restrict__ out_attrs)
{
  __shared__ __align__(16) f16 ldsA[3 * 16384];   // 98,304 B (depth-2 A)
  __shared__ __align__(16) f16 ldsB[2 * 16384];   // 65,536 B

  const int tid  = threadIdx.x;
  const int lane = tid & 63;
  const int wave = tid >> 6;
  const int wm = wave >> 2, wn = wave & 3;
  const int m16 = lane & 15, quad = lane >> 4;
  const int bm = blockIdx.x, bn = blockIdx.y;
  const int K = 640, NT = 10;

  const int sr = lane >> 3;
  const int ss = (lane & 7) ^ sr;
  const f16* gA[4]; const f16* gB[4];
#pragma unroll
  for (int i = 0; i < 4; ++i) {
    gA[i] = aux_cat + (size_t)(bm * 256 + i * 64 + wave * 8 + sr) * K + ss * 8;
    gB[i] = W_heads + (size_t)(bn * 256 + i * 64 + wave * 8 + sr) * K + ss * 8;
  }
  f16* sA = ldsA + wave * 512;
  f16* sB = ldsB + wave * 512;

  const int aBase = (wm * 128 + m16) * 64;
  const int bBase = (wn * 64  + m16) * 64;
  const int sw0 = ((quad)     ^ (m16 & 7)) * 8;
  const int sw1 = ((4 | quad) ^ (m16 & 7)) * 8;

  f32x4 acc[8][4] = {};
  f16x8 af[4], bf[4];

#define SA4(tt, bA) do { const int k0w = (tt) << 6;                             \
    async16(sA + (bA) + 0 * 4096, gA[0] + k0w);                                 \
    async16(sA + (bA) + 1 * 4096, gA[1] + k0w);                                 \
    async16(sA + (bA) + 2 * 4096, gA[2] + k0w);                                 \
    async16(sA + (bA) + 3 * 4096, gA[3] + k0w); } while (0)
#define SB4(tt, bB) do { const int k0w = (tt) << 6;                             \
    async16(sB + (bB) + 0 * 4096, gB[0] + k0w);                                 \
    async16(sB + (bB) + 1 * 4096, gB[1] + k0w);                                 \
    async16(sB + (bB) + 2 * 4096, gB[2] + k0w);                                 \
    async16(sB + (bB) + 3 * 4096, gB[3] + k0w); } while (0)
#define RDA(mqv, sw, bA) { _Pragma("unroll")                                    \
  for (int ii = 0; ii < 4; ++ii)                                                \
    af[ii] = *(const f16x8*)&ldsA[(bA) + aBase + (mqv) * 4096 + ii * 1024 + (sw)]; }
#define RDB(sw, bB) { _Pragma("unroll")                                         \
  for (int j = 0; j < 4; ++j)                                                   \
    bf[j] = *(const f16x8*)&ldsB[(bB) + bBase + j * 1024 + (sw)]; }
#define MM(mqv) { _Pragma("unroll")                                             \
  for (int ii = 0; ii < 4; ++ii) { _Pragma("unroll")                            \
    for (int j = 0; j < 4; ++j)                                                 \
      acc[(mqv) * 4 + ii][j] = __builtin_amdgcn_mfma_f32_16x16x32_f16(          \
          af[ii], bf[j], acc[(mqv) * 4 + ii][j], 0, 0, 0); } }
#define SBAR __builtin_amdgcn_sched_barrier(0)
#define VM4  asm volatile("s_waitcnt vmcnt(4)" ::: "memory")
#define VM0  asm volatile("s_waitcnt vmcnt(0)" ::: "memory")
#define BAR  __builtin_amdgcn_s_barrier()
#define PRIO1 __builtin_amdgcn_s_setprio(1)
#define PRIO0 __builtin_amdgcn_s_setprio(0)

  // prologue: A(0), B(0), A(1); vmcnt(4) retires A(0)+B(0), A(1) flies.
  SA4(0, 0);
  SBAR;
  SB4(0, 0);
  SBAR;
  SA4(1, 16384);
  VM4;
  BAR;

  int a0 = 0, a1 = 16384, a2 = 32768, b0 = 0;
  for (int t = 0; t < NT; ++t) {
    const bool st1 = (t + 1 < NT), st2 = (t + 2 < NT);

    if (st1) SB4(t + 1, b0 ^ 16384);
    SBAR;
    if (st2) SA4(t + 2, a2);
    RDB(sw0, b0); RDA(0, sw0, a0);
    PRIO1; MM(0); PRIO0;
    RDA(1, sw0, a0);
    PRIO1; MM(1); PRIO0;
    RDB(sw1, b0); RDA(0, sw1, a0);
    PRIO1; MM(0); PRIO0;
    RDA(1, sw1, a0);
    PRIO1; MM(1); PRIO0;
    if (st2) VM4; else VM0;    // retire A(t+1)+B(t+1); A(t+2) keeps flying
    BAR;                       // single per-tile barrier
    int rot = a0; a0 = a1; a1 = a2; a2 = rot;
    b0 ^= 16384;
  }
#undef SA4
#undef SB4
#undef RDA
#undef RDB
#undef MM
#undef SBAR
#undef VM4
#undef VM0
#undef BAR
#undef PRIO1
#undef PRIO0

  const int row0 = bm * 256 + wm * 128 + quad * 4;
  const int colT = bn * 256 + wn * 64 + m16;
#pragma unroll
  for (int ai = 0; ai < 8; ++ai)
#pragma unroll
    for (int j = 0; j < 4; ++j) {
      const int col = colT + j * 16;
      const float bcol = bias_heads[col];
#pragma unroll
      for (int r = 0; r < 4; ++r) {
        const int row = row0 + ai * 16 + r;
        float v = acc[ai][j][r] + bcol;
        if (col < 20)        out_upos[(size_t)row * 20 + col] = v;
        else if (col < 320)  out_xpos[(size_t)row * 300 + col - 20] = v;
        else if (col < 820)  out_attrs[(size_t)row * 500 + col - 320] = v;
      }
    }

  // ---- arcs: 64 rows per block, 512 threads = one full row per pass ----
  const int r0 = bm * 256 + bn * 64;
  const float bh = b_head[0];
  const float s2v = s2[((r0 >> 9) << 9) + tid];
  for (int rl = 0; rl < 64; ++rl) {
    const int row = r0 + rl;
    const float s1v = s1[row] + bh;
    float* orow = out_arcs + (size_t)row * 513;
    if (tid == 0) orow[0] = 0.f;
    orow[1 + tid] = s1v + s2v;
  }
}

// ---------------------------------------------------------------------------
extern "C" void kernel_launch(void* const* d_in, const int* in_sizes, int n_in,
                              void* d_out, int out_size, void* d_ws, size_t ws_size,
                              hipStream_t stream)
{
  const float* emb      = (const float*)d_in[0];   // [32,512,500]
  const float* hidden   = (const float*)d_in[1];   // [32,512,800]
  const int*   lang_ids = (const int*)d_in[2];     // [32]
  const float* lang_tab = (const float*)d_in[3];   // [8,100]
  const float* W_arc  = (const float*)d_in[4];
  const float* b_arc  = (const float*)d_in[5];
  const float* W_lab  = (const float*)d_in[6];
  const float* b_lab  = (const float*)d_in[7];
  const float* w_head = (const float*)d_in[8];
  const float* b_head = (const float*)d_in[9];
  const float* W_aux  = (const float*)d_in[10];
  const float* b_aux  = (const float*)d_in[11];
  const float* W_upos = (const float*)d_in[12];
  const float* b_upos = (const float*)d_in[13];
  const float* W_xpos = (const float*)d_in[14];
  const float* b_xpos = (const float*)d_in[15];
  const float* W_attrs = (const float*)d_in[16];
  const float* b_attrs = (const float*)d_in[17];

  char* ws = (char*)d_ws;
  f16* aux_cat = (f16*)(ws + 0);                  // 16384*640*2 = 20,971,520
  f16* W_proj  = (f16*)(ws + 20971520);           // 512*640*2   =    655,360
  f16* W_auxp  = (f16*)(ws + 21626880);           // 512*832*2   =    851,968
  f16* W_heads = (f16*)(ws + 22478848);           // 1024*640*2  =  1,310,720
  float* bias_proj  = (float*)(ws + 23789568);    // 512*4
  float* bias_aux   = (float*)(ws + 23791616);    // 512*4
  float* bias_heads = (float*)(ws + 23793664);    // 1024*4
  float* s1         = (float*)(ws + 23797760);    // 16384*4
  float* s2         = (float*)(ws + 23863296);    // 16384*4
  // total ws use: 23,928,832 bytes

  float* out       = (float*)d_out;
  float* out_arcs  = out;                 // 8,404,992
  float* out_label = out + 8404992;       // 6,553,600
  float* out_upos  = out + 14958592;      //   327,680
  float* out_xpos  = out + 15286272;      // 4,915,200
  float* out_attrs = out + 20201472;      // 8,192,000

  setup_kernel<<<1377, 256, 0, stream>>>(
      W_arc, b_arc, W_lab, b_lab, W_aux, b_aux,
      W_upos, b_upos, W_xpos, b_xpos, W_attrs, b_attrs,
      W_proj, W_auxp, W_heads, bias_proj, bias_aux, bias_heads);

  gemm01<<<dim3(64, 4), 512, 0, stream>>>(
      emb, hidden, lang_tab, lang_ids, W_proj, W_auxp, bias_proj, bias_aux,
      out_label, w_head, s1, s2, aux_cat);

  gemm2_arcs<<<dim3(64, 4), 512, 0, stream>>>(
      aux_cat, W_heads, bias_heads, s1, s2, b_head,
      out_arcs, out_upos, out_xpos, out_attrs);
}

// Round 9
// 270.208 us; speedup vs baseline: 1.1571x; 1.0365x over previous
//
#include <hip/hip_runtime.h>

// ===== Problem dims =====
// B=32, L=512 -> M = 16384 rows. Inputs fp32, OUTPUTS fp32.
// GEMM1(proj): A=[emb|lang] K=640 (reg-staged fp32->f16), N=512 pad, tanh,
//   fused s1/s2. GEMM1b(aux): A=hidden K=800 pad 832 (reg-staged), tanh,
//   writes aux_cat (+lang/pad cols from bny==2 epilogue).
// GEMM2(heads): A=aux_cat f16 (async16 DEPTH-2), N=820 pad 1024, arcs fused.
// R9 = composition of measured winners:
//   gemm01 = R6 exactly (70us: free-run 1 barrier/tile, A-pin discipline,
//            2x2 LDS buffers, separate s1red/s2red arrays, 135KB LDS).
//   gemm2  = R8 exactly (depth-2 A prefetch, 3 A-bufs + 2 B-bufs = 160KB,
//            end-of-tile vmcnt(4), vmcnt(0) only at edges).
// 3 launches: setup(weights+bias) -> gemm01 (64x4) -> gemm2+arcs (64x4).

using f16   = _Float16;
using f16x4 = __attribute__((ext_vector_type(4))) _Float16;
using f16x8 = __attribute__((ext_vector_type(8))) _Float16;  // 8 f16 (4 VGPRs)
using f32x4 = __attribute__((ext_vector_type(4))) float;     // MFMA acc

__device__ __forceinline__ f16 f2h(float f) { return (f16)f; }
__device__ __forceinline__ f16x4 cvt4(float4 v) {
  return f16x4{ f2h(v.x), f2h(v.y), f2h(v.z), f2h(v.w) };
}

// fast tanh: 1 - 2/(2^(2x*log2e)+1)
__device__ __forceinline__ float fast_tanh(float x) {
  float xc = fminf(fmaxf(x, -15.f), 15.f);
  float e  = __builtin_amdgcn_exp2f(xc * 2.885390081777927f);
  return 1.f - 2.f * __builtin_amdgcn_rcpf(e + 1.f);
}

// async global->LDS, 16B/lane; LDS dest = wave-uniform base + lane*16
__device__ __forceinline__ void async16(void* lds, const void* gp) {
  __builtin_amdgcn_global_load_lds(
      (const __attribute__((address_space(1))) unsigned int*)gp,
      (__attribute__((address_space(3))) unsigned int*)lds, 16, 0, 0);
}

// ---------------------------------------------------------------------------
// Setup (tiny): pack f16 weights + fp32 biases only.
//   W_proj[512,640] | W_auxp[512,832] | W_heads[1024,640]
// ---------------------------------------------------------------------------
__global__ __launch_bounds__(256) void setup_kernel(
    const float* __restrict__ W_arc, const float* __restrict__ b_arc,
    const float* __restrict__ W_lab, const float* __restrict__ b_lab,
    const float* __restrict__ W_aux, const float* __restrict__ b_aux,
    const float* __restrict__ W_upos, const float* __restrict__ b_upos,
    const float* __restrict__ W_xpos, const float* __restrict__ b_xpos,
    const float* __restrict__ W_attrs, const float* __restrict__ b_attrs,
    f16* __restrict__ W_proj, f16* __restrict__ W_auxp, f16* __restrict__ W_heads,
    float* __restrict__ bias_proj, float* __restrict__ bias_aux, float* __restrict__ bias_heads)
{
  const int blk = blockIdx.x, t = threadIdx.x;
  if (blk < 1376) {                          // 352,256 weight quads
    int w = blk * 256 + t;
    const float* src = nullptr;
    f16* dst;
    if (w < 81920) {                         // W_proj [512,640] : 160 q/row
      int n = w / 160, s = w - n * 160;
      dst = W_proj + (size_t)w * 4;
      if (s < 150 && n < 500)
        src = (n < 100 ? W_arc + (size_t)n * 600
                       : W_lab + (size_t)(n - 100) * 600) + s * 4;
    } else if (w < 81920 + 106496) {         // W_auxp [512,832] : 208 q/row
      int w2 = w - 81920;
      int n = w2 / 208, s = w2 - n * 208;
      dst = W_auxp + (size_t)w2 * 4;
      if (s < 200 && n < 500) src = W_aux + (size_t)n * 800 + s * 4;
    } else {                                 // W_heads [1024,640] : 160 q/row
      int w3 = w - (81920 + 106496);
      int n = w3 / 160, s = w3 - n * 160;
      dst = W_heads + (size_t)w3 * 4;
      if (s < 150 && n < 820)
        src = (n < 20 ? W_upos + (size_t)n * 600
              : n < 320 ? W_xpos + (size_t)(n - 20) * 600
                        : W_attrs + (size_t)(n - 320) * 600) + s * 4;
    }
    f16x4 h = { (f16)0.f, (f16)0.f, (f16)0.f, (f16)0.f };
    if (src) h = cvt4(*(const float4*)src);
    *(f16x4*)dst = h;
    return;
  }
  for (int idx = t; idx < 2048; idx += 256) {      // ---- biases ----
    if (idx < 512) {
      float v = 0.f;
      if (idx < 100)      v = b_arc[idx];
      else if (idx < 500) v = b_lab[idx - 100];
      bias_proj[idx] = v;
    } else if (idx < 1024) {
      int i = idx - 512;
      bias_aux[i] = (i < 500) ? b_aux[i] : 0.f;
    } else {
      int i = idx - 1024; float v = 0.f;
      if (i < 20)       v = b_upos[i];
      else if (i < 320) v = b_xpos[i - 20];
      else if (i < 820) v = b_attrs[i - 320];
      bias_heads[i] = v;
    }
  }
}

// ---------------------------------------------------------------------------
// Fused GEMM0+GEMM1 (R6 verbatim), grid (64, 4), 512 threads.
//   bny<2 : proj A=[emb|lang|pad] K=640 NT=10; cols[100,500)->out_label;
//           bny==0: fused s1/s2 head dots
//   bny>=2: aux  A=hidden pad     K=832 NT=13; cols[0,500)->aux_cat;
//           bny==2 also writes aux_cat lang/pad cols [500,640)
// ---------------------------------------------------------------------------
__global__ __launch_bounds__(512, 2) void gemm01(
    const float* __restrict__ emb, const float* __restrict__ hidden,
    const float* __restrict__ lang_table, const int* __restrict__ lang_ids,
    const f16* __restrict__ W_proj, const f16* __restrict__ W_auxp,
    const float* __restrict__ bias_proj, const float* __restrict__ bias_aux,
    float* __restrict__ out_label, const float* __restrict__ w_head,
    float* __restrict__ s1, float* __restrict__ s2, f16* __restrict__ aux_cat)
{
  __shared__ __align__(16) f16 ldsA[2 * 16384];
  __shared__ __align__(16) f16 ldsB[2 * 16384];
  __shared__ float s1red[2][256], s2red[2][256];

  const int tid  = threadIdx.x;
  const int lane = tid & 63;
  const int wave = tid >> 6;                 // 0..7
  const int wm = wave >> 2, wn = wave & 3;   // 2M x 4N
  const int m16 = lane & 15, quad = lane >> 4;
  const int bm  = blockIdx.x;
  const int bny = blockIdx.y;                // 0..3
  const bool is0 = (bny < 2);
  const int bn  = is0 ? bny : bny - 2;
  const int K   = is0 ? 640 : 832;
  const int NT  = is0 ? 10 : 13;

  // ---- B staging (async16, pre-swizzled source) ----
  const int sr = lane >> 3;
  const int ssB = (lane & 7) ^ sr;
  const f16* Bmat = is0 ? W_proj : W_auxp;
  const f16* gB[4];
#pragma unroll
  for (int i = 0; i < 4; ++i)
    gB[i] = Bmat + (size_t)(bn * 256 + i * 64 + wave * 8 + sr) * K + ssB * 8;
  f16* sB = ldsB + wave * 512;

  // ---- A reg-staging: lane owns 4 chunks (rows wave*32+i*8+(lane>>3),
  //      slot ssA=lane&7); lang row is block-uniform (batch = bm>>1). ----
  const int ssA = lane & 7;
  const float* lrow = lang_table + (size_t)lang_ids[bm >> 1] * 100;
  const float* srcA[4];
  int dstA[4];
#pragma unroll
  for (int i = 0; i < 4; ++i) {
    const int rowA = wave * 32 + i * 8 + (lane >> 3);
    const int grow = bm * 256 + rowA;
    srcA[i] = is0 ? emb + (size_t)grow * 500 : hidden + (size_t)grow * 800;
    dstA[i] = rowA * 64 + ((ssA ^ (rowA & 7)) * 8);
  }
  float4 va[4], vb[4];

  // ---- ds_read bases ----
  const int aBase = (wm * 128 + m16) * 64;
  const int bBase = (wn * 64  + m16) * 64;
  const int sw0 = ((quad)     ^ (m16 & 7)) * 8;
  const int sw1 = ((4 | quad) ^ (m16 & 7)) * 8;

  f32x4 acc[8][4] = {};
  f16x8 af[4], bf[4];

#define ASTAGE(tt) do { const int k0b = (tt) * 64 + ssA * 8;                    \
    _Pragma("unroll")                                                           \
    for (int i2 = 0; i2 < 4; ++i2) {                                            \
      float4 x0 = {0.f,0.f,0.f,0.f}, x1 = {0.f,0.f,0.f,0.f};                    \
      if (is0) {                                                                \
        if (k0b < 500) { x0 = *(const float4*)(srcA[i2] + k0b);                 \
          x1 = (k0b + 4 < 500) ? *(const float4*)(srcA[i2] + k0b + 4)           \
                               : *(const float4*)(lrow); }                      \
        else if (k0b < 600) { x0 = *(const float4*)(lrow + k0b - 500);          \
                              x1 = *(const float4*)(lrow + k0b - 496); }        \
      } else if (k0b < 800) { x0 = *(const float4*)(srcA[i2] + k0b);            \
                              x1 = *(const float4*)(srcA[i2] + k0b + 4); }      \
      va[i2] = x0; vb[i2] = x1; } } while (0)

#define AWRITE(nbf) do { _Pragma("unroll")                                      \
    for (int i2 = 0; i2 < 4; ++i2) {                                            \
      f16x8 hw = { f2h(va[i2].x), f2h(va[i2].y), f2h(va[i2].z), f2h(va[i2].w),  \
                   f2h(vb[i2].x), f2h(vb[i2].y), f2h(vb[i2].z), f2h(vb[i2].w) };\
      *(f16x8*)&ldsA[(nbf) + dstA[i2]] = hw; } } while (0)

#define BWISSUE(k0n, nbf) do {                                                  \
    async16(sB + (nbf) + 0 * 4096, gB[0] + (k0n));                              \
    async16(sB + (nbf) + 1 * 4096, gB[1] + (k0n));                              \
    async16(sB + (nbf) + 2 * 4096, gB[2] + (k0n));                              \
    async16(sB + (nbf) + 3 * 4096, gB[3] + (k0n)); } while (0)

#define RDA(mqv, sw) { _Pragma("unroll")                                        \
  for (int ii = 0; ii < 4; ++ii)                                                \
    af[ii] = *(const f16x8*)&ldsA[buf + aBase + (mqv) * 4096 + ii * 1024 + (sw)]; }
#define RDB(sw) { _Pragma("unroll")                                             \
  for (int j = 0; j < 4; ++j)                                                   \
    bf[j] = *(const f16x8*)&ldsB[buf + bBase + j * 1024 + (sw)]; }
#define MM(mqv) { _Pragma("unroll")                                             \
  for (int ii = 0; ii < 4; ++ii) { _Pragma("unroll")                            \
    for (int j = 0; j < 4; ++j)                                                 \
      acc[(mqv) * 4 + ii][j] = __builtin_amdgcn_mfma_f32_16x16x32_f16(          \
          af[ii], bf[j], acc[(mqv) * 4 + ii][j], 0, 0, 0); } }
#define SBAR __builtin_amdgcn_sched_barrier(0)
#define VM4  asm volatile("s_waitcnt vmcnt(4)" ::: "memory")
#define VM0  asm volatile("s_waitcnt vmcnt(0)" ::: "memory")
#define LGK0 asm volatile("s_waitcnt lgkmcnt(0)" ::: "memory")
#define BAR  __builtin_amdgcn_s_barrier()
#define PRIO1 __builtin_amdgcn_s_setprio(1)
#define PRIO0 __builtin_amdgcn_s_setprio(0)

  // ---- prologue: tile 0. A-loads first (issue-order pinned), then B
  //      async16; vmcnt(4) => all A landed, async16 still flying. ----
  ASTAGE(0);
  SBAR;
  BWISSUE(0, 0);
  SBAR; VM4; SBAR;
  AWRITE(0);
  VM0;
  LGK0;
  BAR;

  for (int t = 0; t < NT; ++t) {
    const int buf = (t & 1) << 14;           // *16384
    const int nbf = ((t + 1) & 1) << 14;
    const bool st = (t + 1 < NT);
    const int k0n = (t + 1) << 6;

    // ---- free-run tile body: no intra-tile barriers ----
    RDB(sw0); RDA(0, sw0);
    if (st) ASTAGE(t + 1);
    SBAR;                      // A-loads issue before B async16
    if (st) BWISSUE(k0n, nbf);
    PRIO1; MM(0); PRIO0;
    RDA(1, sw0);
    PRIO1; MM(1); PRIO0;
    RDB(sw1); RDA(0, sw1);
    PRIO1; MM(0); PRIO0;
    RDA(1, sw1);
    PRIO1; MM(1); PRIO0;
    if (st) {
      SBAR; VM4; SBAR;         // all 8 A-loads retired; 4 async16 in flight
      AWRITE(nbf);
    }
    VM0;                       // retire async16(t+1) -> publish ldsB[nbf]
    LGK0;                      // publish AWRITE ds_writes
    BAR;                       // single per-tile barrier
  }
#undef ASTAGE
#undef AWRITE
#undef BWISSUE
#undef RDA
#undef RDB
#undef MM
#undef SBAR
#undef VM4
#undef VM0
#undef LGK0
#undef BAR
#undef PRIO1
#undef PRIO0

  // ---- epilogue ----
  const int row0 = bm * 256 + wm * 128 + quad * 4;
  const int colT = bn * 256 + wn * 64 + m16;

  if (is0) {
    const float* bias = bias_proj;
    float p1[8][4] = {}, p2[8][4] = {};
    const bool haveHead = (bn == 0);
#pragma unroll
    for (int ai = 0; ai < 8; ++ai) {
#pragma unroll
      for (int j = 0; j < 4; ++j) {
        const int col = colT + j * 16;
        const float bcol = bias[col];
        float w1c = 0.f, w2c = 0.f;
        if (haveHead && col < 100) { w1c = w_head[col]; w2c = w_head[100 + col]; }
#pragma unroll
        for (int r = 0; r < 4; ++r) {
          const int row = row0 + ai * 16 + r;
          float v = fast_tanh(acc[ai][j][r] + bcol);
          if (col >= 100 && col < 500) out_label[(size_t)row * 400 + col - 100] = v;
          p1[ai][r] += v * w1c;
          p2[ai][r] += v * w2c;
        }
      }
    }
    if (haveHead) {
      if (wn < 2) {
#pragma unroll
        for (int d = 1; d < 16; d <<= 1)
#pragma unroll
          for (int ai = 0; ai < 8; ++ai)
#pragma unroll
            for (int r = 0; r < 4; ++r) {
              p1[ai][r] += __shfl_xor(p1[ai][r], d);
              p2[ai][r] += __shfl_xor(p2[ai][r], d);
            }
        if (m16 == 0) {
#pragma unroll
          for (int ai = 0; ai < 8; ++ai)
#pragma unroll
            for (int r = 0; r < 4; ++r) {
              int rl = wm * 128 + ai * 16 + quad * 4 + r;
              s1red[wn][rl] = p1[ai][r];
              s2red[wn][rl] = p2[ai][r];
            }
        }
      }
      __syncthreads();
      if (tid < 256) s1[bm * 256 + tid] = s1red[0][tid] + s1red[1][tid];
      else { int t2 = tid - 256; s2[bm * 256 + t2] = s2red[0][t2] + s2red[1][t2]; }
    }
  } else {
    const float* bias = bias_aux;
#pragma unroll
    for (int ai = 0; ai < 8; ++ai)
#pragma unroll
      for (int j = 0; j < 4; ++j) {
        const int col = colT + j * 16;
        if (col < 500) {
          const float bcol = bias[col];
#pragma unroll
          for (int r = 0; r < 4; ++r) {
            const int row = row0 + ai * 16 + r;
            aux_cat[(size_t)row * 640 + col] = f2h(fast_tanh(acc[ai][j][r] + bcol));
          }
        }
      }
    if (bn == 0) {                           // bny==2: lang/pad cols [500,640)
      for (int idx = tid; idx < 256 * 35; idx += 512) {
        int rr = idx / 35, qq = idx - rr * 35;
        int col = 500 + 4 * qq;
        f16x4 h = { (f16)0.f, (f16)0.f, (f16)0.f, (f16)0.f };
        if (col < 600) h = cvt4(*(const float4*)(lrow + col - 500));
        *(f16x4*)(aux_cat + (size_t)(bm * 256 + rr) * 640 + col) = h;
      }
    }
  }
}

// ---------------------------------------------------------------------------
// Fused GEMM2 + arcs (R8 verbatim), grid (64, 4), 512 threads, free-run
// 1-barrier/tile. A depth-2 (3 bufs, 96KB) + B depth-1 (2 bufs, 64KB) =
// 160KB LDS. End-of-tile vmcnt(4) (A(t+2) stays in flight); vmcnt(0) edges.
//   heads GEMM A=aux_cat[16384,640] B=W_heads[1024,640] K=640 NT=10;
//   cols<20 upos | <320 xpos | <820 attrs. Then arcs rows [bm*256+bn*64,+64).
// ---------------------------------------------------------------------------
__global__ __launch_bounds__(512, 2) void gemm2_arcs(
    const f16* __restrict__ aux_cat, const f16* __restrict__ W_heads,
    const float* __restrict__ bias_heads,
    const float* __restrict__ s1, const float* __restrict__ s2,
    const float* __restrict__ b_head,
    float* __restrict__ out_arcs, float* __restrict__ out_upos,
    float* __restrict__ out_xpos, float* __restrict__ out_attrs)
{
  __shared__ __align__(16) f16 ldsA[3 * 16384];   // 98,304 B (depth-2 A)
  __shared__ __align__(16) f16 ldsB[2 * 16384];   // 65,536 B

  const int tid  = threadIdx.x;
  const int lane = tid & 63;
  const int wave = tid >> 6;
  const int wm = wave >> 2, wn = wave & 3;
  const int m16 = lane & 15, quad = lane >> 4;
  const int bm = blockIdx.x, bn = blockIdx.y;
  const int K = 640, NT = 10;

  const int sr = lane >> 3;
  const int ss = (lane & 7) ^ sr;
  const f16* gA[4]; const f16* gB[4];
#pragma unroll
  for (int i = 0; i < 4; ++i) {
    gA[i] = aux_cat + (size_t)(bm * 256 + i * 64 + wave * 8 + sr) * K + ss * 8;
    gB[i] = W_heads + (size_t)(bn * 256 + i * 64 + wave * 8 + sr) * K + ss * 8;
  }
  f16* sA = ldsA + wave * 512;
  f16* sB = ldsB + wave * 512;

  const int aBase = (wm * 128 + m16) * 64;
  const int bBase = (wn * 64  + m16) * 64;
  const int sw0 = ((quad)     ^ (m16 & 7)) * 8;
  const int sw1 = ((4 | quad) ^ (m16 & 7)) * 8;

  f32x4 acc[8][4] = {};
  f16x8 af[4], bf[4];

#define SA4(tt, bA) do { const int k0w = (tt) << 6;                             \
    async16(sA + (bA) + 0 * 4096, gA[0] + k0w);                                 \
    async16(sA + (bA) + 1 * 4096, gA[1] + k0w);                                 \
    async16(sA + (bA) + 2 * 4096, gA[2] + k0w);                                 \
    async16(sA + (bA) + 3 * 4096, gA[3] + k0w); } while (0)
#define SB4(tt, bB) do { const int k0w = (tt) << 6;                             \
    async16(sB + (bB) + 0 * 4096, gB[0] + k0w);                                 \
    async16(sB + (bB) + 1 * 4096, gB[1] + k0w);                                 \
    async16(sB + (bB) + 2 * 4096, gB[2] + k0w);                                 \
    async16(sB + (bB) + 3 * 4096, gB[3] + k0w); } while (0)
#define RDA(mqv, sw, bA) { _Pragma("unroll")                                    \
  for (int ii = 0; ii < 4; ++ii)                                                \
    af[ii] = *(const f16x8*)&ldsA[(bA) + aBase + (mqv) * 4096 + ii * 1024 + (sw)]; }
#define RDB(sw, bB) { _Pragma("unroll")                                         \
  for (int j = 0; j < 4; ++j)                                                   \
    bf[j] = *(const f16x8*)&ldsB[(bB) + bBase + j * 1024 + (sw)]; }
#define MM(mqv) { _Pragma("unroll")                                             \
  for (int ii = 0; ii < 4; ++ii) { _Pragma("unroll")                            \
    for (int j = 0; j < 4; ++j)                                                 \
      acc[(mqv) * 4 + ii][j] = __builtin_amdgcn_mfma_f32_16x16x32_f16(          \
          af[ii], bf[j], acc[(mqv) * 4 + ii][j], 0, 0, 0); } }
#define SBAR __builtin_amdgcn_sched_barrier(0)
#define VM4  asm volatile("s_waitcnt vmcnt(4)" ::: "memory")
#define VM0  asm volatile("s_waitcnt vmcnt(0)" ::: "memory")
#define BAR  __builtin_amdgcn_s_barrier()
#define PRIO1 __builtin_amdgcn_s_setprio(1)
#define PRIO0 __builtin_amdgcn_s_setprio(0)

  // prologue: A(0), B(0), A(1); vmcnt(4) retires A(0)+B(0), A(1) flies.
  SA4(0, 0);
  SBAR;
  SB4(0, 0);
  SBAR;
  SA4(1, 16384);
  VM4;
  BAR;

  int a0 = 0, a1 = 16384, a2 = 32768, b0 = 0;
  for (int t = 0; t < NT; ++t) {
    const bool st1 = (t + 1 < NT), st2 = (t + 2 < NT);

    if (st1) SB4(t + 1, b0 ^ 16384);
    SBAR;
    if (st2) SA4(t + 2, a2);
    RDB(sw0, b0); RDA(0, sw0, a0);
    PRIO1; MM(0); PRIO0;
    RDA(1, sw0, a0);
    PRIO1; MM(1); PRIO0;
    RDB(sw1, b0); RDA(0, sw1, a0);
    PRIO1; MM(0); PRIO0;
    RDA(1, sw1, a0);
    PRIO1; MM(1); PRIO0;
    if (st2) VM4; else VM0;    // retire A(t+1)+B(t+1); A(t+2) keeps flying
    BAR;                       // single per-tile barrier
    int rot = a0; a0 = a1; a1 = a2; a2 = rot;
    b0 ^= 16384;
  }
#undef SA4
#undef SB4
#undef RDA
#undef RDB
#undef MM
#undef SBAR
#undef VM4
#undef VM0
#undef BAR
#undef PRIO1
#undef PRIO0

  const int row0 = bm * 256 + wm * 128 + quad * 4;
  const int colT = bn * 256 + wn * 64 + m16;
#pragma unroll
  for (int ai = 0; ai < 8; ++ai)
#pragma unroll
    for (int j = 0; j < 4; ++j) {
      const int col = colT + j * 16;
      const float bcol = bias_heads[col];
#pragma unroll
      for (int r = 0; r < 4; ++r) {
        const int row = row0 + ai * 16 + r;
        float v = acc[ai][j][r] + bcol;
        if (col < 20)        out_upos[(size_t)row * 20 + col] = v;
        else if (col < 320)  out_xpos[(size_t)row * 300 + col - 20] = v;
        else if (col < 820)  out_attrs[(size_t)row * 500 + col - 320] = v;
      }
    }

  // ---- arcs: 64 rows per block, 512 threads = one full row per pass ----
  const int r0 = bm * 256 + bn * 64;
  const float bh = b_head[0];
  const float s2v = s2[((r0 >> 9) << 9) + tid];
  for (int rl = 0; rl < 64; ++rl) {
    const int row = r0 + rl;
    const float s1v = s1[row] + bh;
    float* orow = out_arcs + (size_t)row * 513;
    if (tid == 0) orow[0] = 0.f;
    orow[1 + tid] = s1v + s2v;
  }
}

// ---------------------------------------------------------------------------
extern "C" void kernel_launch(void* const* d_in, const int* in_sizes, int n_in,
                              void* d_out, int out_size, void* d_ws, size_t ws_size,
                              hipStream_t stream)
{
  const float* emb      = (const float*)d_in[0];   // [32,512,500]
  const float* hidden   = (const float*)d_in[1];   // [32,512,800]
  const int*   lang_ids = (const int*)d_in[2];     // [32]
  const float* lang_tab = (const float*)d_in[3];   // [8,100]
  const float* W_arc  = (const float*)d_in[4];
  const float* b_arc  = (const float*)d_in[5];
  const float* W_lab  = (const float*)d_in[6];
  const float* b_lab  = (const float*)d_in[7];
  const float* w_head = (const float*)d_in[8];
  const float* b_head = (const float*)d_in[9];
  const float* W_aux  = (const float*)d_in[10];
  const float* b_aux  = (const float*)d_in[11];
  const float* W_upos = (const float*)d_in[12];
  const float* b_upos = (const float*)d_in[13];
  const float* W_xpos = (const float*)d_in[14];
  const float* b_xpos = (const float*)d_in[15];
  const float* W_attrs = (const float*)d_in[16];
  const float* b_attrs = (const float*)d_in[17];

  char* ws = (char*)d_ws;
  f16* aux_cat = (f16*)(ws + 0);                  // 16384*640*2 = 20,971,520
  f16* W_proj  = (f16*)(ws + 20971520);           // 512*640*2   =    655,360
  f16* W_auxp  = (f16*)(ws + 21626880);           // 512*832*2   =    851,968
  f16* W_heads = (f16*)(ws + 22478848);           // 1024*640*2  =  1,310,720
  float* bias_proj  = (float*)(ws + 23789568);    // 512*4
  float* bias_aux   = (float*)(ws + 23791616);    // 512*4
  float* bias_heads = (float*)(ws + 23793664);    // 1024*4
  float* s1         = (float*)(ws + 23797760);    // 16384*4
  float* s2         = (float*)(ws + 23863296);    // 16384*4
  // total ws use: 23,928,832 bytes

  float* out       = (float*)d_out;
  float* out_arcs  = out;                 // 8,404,992
  float* out_label = out + 8404992;       // 6,553,600
  float* out_upos  = out + 14958592;      //   327,680
  float* out_xpos  = out + 15286272;      // 4,915,200
  float* out_attrs = out + 20201472;      // 8,192,000

  setup_kernel<<<1377, 256, 0, stream>>>(
      W_arc, b_arc, W_lab, b_lab, W_aux, b_aux,
      W_upos, b_upos, W_xpos, b_xpos, W_attrs, b_attrs,
      W_proj, W_auxp, W_heads, bias_proj, bias_aux, bias_heads);

  gemm01<<<dim3(64, 4), 512, 0, stream>>>(
      emb, hidden, lang_tab, lang_ids, W_proj, W_auxp, bias_proj, bias_aux,
      out_label, w_head, s1, s2, aux_cat);

  gemm2_arcs<<<dim3(64, 4), 512, 0, stream>>>(
      aux_cat, W_heads, bias_heads, s1, s2, b_head,
      out_arcs, out_upos, out_xpos, out_attrs);
}